// Round 1
// baseline (1407.660 us; speedup 1.0000x reference)
//
#include <hip/hip_runtime.h>
#include <cmath>

typedef _Float16 v8h __attribute__((ext_vector_type(8)));
typedef float v4f __attribute__((ext_vector_type(4)));

#define DEV __device__ __forceinline__

// token index map for shifted-window partition: window-order row m -> spatial token l
DEV int win_map(int m) {
  int w = m >> 6, tok = m & 63;
  int r = ((w >> 1) * 8 + (tok >> 3) + 4) & 15;
  int c = ((w & 1) * 8 + (tok & 7) + 4) & 15;
  return r * 16 + c;
}

// A-row loader. MAP 0: identity rows (stride K). MAP 1: window-shift map (K=384).
// MAP 2: patch-embed im2col gather from x (1,3,256,256), K=768, j=(inc,p,q).
template<int MAP>
DEV float4 loadA4(const float* __restrict__ A, int m, int k, int K) {
  if constexpr (MAP == 0) {
    return *(const float4*)(A + (size_t)m * K + k);
  } else if constexpr (MAP == 1) {
    return *(const float4*)(A + (size_t)win_map(m) * 384 + k);
  } else {
    int h = m >> 4, w = m & 15;
    int inc = k >> 8, rem = k & 255, p = rem >> 4, q = rem & 15;
    return *(const float4*)(A + inc * 65536 + (h * 16 + p) * 256 + w * 16 + q);
  }
}

// C[m,n] = epilogue( dot(LNopt(A[maprow(m)]), W[n]) )
// EPI 0: plain store. 1: +bias[n]+resid -> Cout. 2: gelu(.+bias[n]). 3: patch store
// transposed Cout[n*256+m] = v + bias[n] + aux[n*256+m].
template<int WAVES_M, int WAVES_N, int WN, int MAP, bool LN, int EPI>
__launch_bounds__(256)
__global__ void mgemm(const float* __restrict__ A, const float* __restrict__ W,
                      const float* __restrict__ bias,
                      const float* __restrict__ lnw, const float* __restrict__ lnb,
                      const float* __restrict__ resid, const float* __restrict__ aux,
                      float* __restrict__ Cout, int N, int K) {
  constexpr int BM = WAVES_M * 16;
  constexpr int BN = WAVES_N * WN * 16;
  constexpr int BK = 64;
  constexpr int BKP = BK + 8;  // half padding: 144B rows, 16B-aligned, ~2-way banks

  __shared__ _Float16 As[BM][BKP];
  __shared__ _Float16 Ws[BN][BKP];
  __shared__ float redS[256], redQ[256];
  __shared__ float lmean[BM], lrstd[BM];

  const int t = threadIdx.x;
  const int wave = t >> 6, lane = t & 63;
  const int m0 = blockIdx.y * BM, n0 = blockIdx.x * BN;

  if constexpr (LN) {
    constexpr int PARTS = 256 / BM;
    int r = t / PARTS, part = t % PARTS;
    int chunk = K / PARTS;
    float s = 0.f, sq = 0.f;
    for (int k = part * chunk; k < (part + 1) * chunk; k += 4) {
      float4 v = loadA4<MAP>(A, m0 + r, k, K);
      s += v.x + v.y + v.z + v.w;
      sq += v.x * v.x + v.y * v.y + v.z * v.z + v.w * v.w;
    }
    redS[t] = s; redQ[t] = sq;
    __syncthreads();
    if (t < BM) {
      float ss = 0.f, qq = 0.f;
      for (int p = 0; p < PARTS; ++p) { ss += redS[t * PARTS + p]; qq += redQ[t * PARTS + p]; }
      float mean = ss / K;
      float var = qq / K - mean * mean;
      lmean[t] = mean;
      lrstd[t] = rsqrtf(var + 1e-5f);
    }
    __syncthreads();
  }

  const int wm = wave % WAVES_M;
  const int wn = wave / WAVES_M;
  const int mBase = wm * 16;
  const int nBase = wn * (WN * 16);

  v4f acc[WN] = {};

  for (int k0 = 0; k0 < K; k0 += BK) {
    constexpr int AREP = (BM * 16) / 256;
#pragma unroll
    for (int i = 0; i < AREP; ++i) {
      int idx = t + i * 256;
      int row = idx >> 4;
      int kc = (idx & 15) * 4;
      float4 v = loadA4<MAP>(A, m0 + row, k0 + kc, K);
      if constexpr (LN) {
        float4 lw = *(const float4*)(lnw + k0 + kc);
        float4 lb = *(const float4*)(lnb + k0 + kc);
        float mu = lmean[row], rs = lrstd[row];
        v.x = (v.x - mu) * rs * lw.x + lb.x;
        v.y = (v.y - mu) * rs * lw.y + lb.y;
        v.z = (v.z - mu) * rs * lw.z + lb.z;
        v.w = (v.w - mu) * rs * lw.w + lb.w;
      }
      _Float16* dst = &As[row][kc];
      dst[0] = (_Float16)v.x; dst[1] = (_Float16)v.y;
      dst[2] = (_Float16)v.z; dst[3] = (_Float16)v.w;
    }
    constexpr int WREP = (BN * 16) / 256;
#pragma unroll
    for (int i = 0; i < WREP; ++i) {
      int idx = t + i * 256;
      int row = idx >> 4;
      int kc = (idx & 15) * 4;
      float4 v = *(const float4*)(W + (size_t)(n0 + row) * K + k0 + kc);
      _Float16* dst = &Ws[row][kc];
      dst[0] = (_Float16)v.x; dst[1] = (_Float16)v.y;
      dst[2] = (_Float16)v.z; dst[3] = (_Float16)v.w;
    }
    __syncthreads();
#pragma unroll
    for (int kk = 0; kk < BK; kk += 32) {
      v8h af = *(const v8h*)&As[mBase + (lane & 15)][kk + (lane >> 4) * 8];
#pragma unroll
      for (int nt = 0; nt < WN; ++nt) {
        v8h bf = *(const v8h*)&Ws[nBase + nt * 16 + (lane & 15)][kk + (lane >> 4) * 8];
        acc[nt] = __builtin_amdgcn_mfma_f32_16x16x32_f16(af, bf, acc[nt], 0, 0, 0);
      }
    }
    __syncthreads();
  }

  const int quad = lane >> 4;
  const int col = lane & 15;
#pragma unroll
  for (int nt = 0; nt < WN; ++nt) {
    int n = n0 + nBase + nt * 16 + col;
#pragma unroll
    for (int r = 0; r < 4; ++r) {
      int m = m0 + mBase + quad * 4 + r;
      float v = acc[nt][r];
      if constexpr (EPI == 0) {
        Cout[(size_t)m * N + n] = v;
      } else if constexpr (EPI == 1) {
        Cout[(size_t)m * N + n] = resid[(size_t)m * N + n] + v + bias[n];
      } else if constexpr (EPI == 2) {
        float z = v + bias[n];
        Cout[(size_t)m * N + n] = 0.5f * z * (1.0f + erff(z * 0.70710678118654752f));
      } else {
        Cout[n * 256 + m] = v + bias[n] + aux[n * 256 + m];
      }
    }
  }
}

// windowed attention: one block per (window, head). qkv: (256 win-rows, 1152).
__launch_bounds__(256)
__global__ void attn_k(const float* __restrict__ qkv, const float* __restrict__ rpb,
                       float* __restrict__ obuf) {
  __shared__ float qs[64][33], ks[64][33], vs[64][33];
  __shared__ float ps[64][68];
  __shared__ float rbias[225];
  __shared__ int labv[64];
  const int t = threadIdx.x;
  const int w = blockIdx.x & 3, head = blockIdx.x >> 2;

  for (int idx = t; idx < 2048; idx += 256) {
    int tok = idx >> 5, d = idx & 31;
    int base = (w * 64 + tok) * 1152 + head * 32 + d;
    qs[tok][d] = qkv[base];
    ks[tok][d] = qkv[base + 384];
    vs[tok][d] = qkv[base + 768];
  }
  for (int idx = t; idx < 225; idx += 256) rbias[idx] = rpb[idx * 12 + head];
  if (t < 64) {
    int r = (w >> 1) * 8 + (t >> 3), c = (w & 1) * 8 + (t & 7);
    int lr = r < 8 ? 0 : (r < 12 ? 1 : 2);
    int lc = c < 8 ? 0 : (c < 12 ? 1 : 2);
    labv[t] = lr * 3 + lc;
  }
  __syncthreads();

  const int tx = t & 15, ty = t >> 4;
  float acc[4][4] = {};
  for (int d = 0; d < 32; ++d) {
    float a[4], b[4];
#pragma unroll
    for (int ii = 0; ii < 4; ++ii) a[ii] = qs[ty * 4 + ii][d];
#pragma unroll
    for (int jj = 0; jj < 4; ++jj) b[jj] = ks[tx * 4 + jj][d];
#pragma unroll
    for (int ii = 0; ii < 4; ++ii)
#pragma unroll
      for (int jj = 0; jj < 4; ++jj) acc[ii][jj] += a[ii] * b[jj];
  }
  const float scale = 0.17677669529663687f;  // 32^-0.5
#pragma unroll
  for (int ii = 0; ii < 4; ++ii) {
    int i = ty * 4 + ii;
    int yi = i >> 3, xi = i & 7, li = labv[i];
    float pv[4];
    float mx = -1e30f;
#pragma unroll
    for (int jj = 0; jj < 4; ++jj) {
      int j = tx * 4 + jj;
      int yj = j >> 3, xj = j & 7;
      int ri = (yi - yj + 7) * 15 + (xi - xj + 7);
      float s = acc[ii][jj] * scale + rbias[ri] + (li == labv[j] ? 0.f : -100.f);
      pv[jj] = s;
      mx = fmaxf(mx, s);
    }
    for (int off = 1; off < 16; off <<= 1) mx = fmaxf(mx, __shfl_xor(mx, off));
    float sum = 0.f;
#pragma unroll
    for (int jj = 0; jj < 4; ++jj) { pv[jj] = expf(pv[jj] - mx); sum += pv[jj]; }
    for (int off = 1; off < 16; off <<= 1) sum += __shfl_xor(sum, off);
    float inv = 1.0f / sum;
#pragma unroll
    for (int jj = 0; jj < 4; ++jj) ps[i][tx * 4 + jj] = pv[jj] * inv;
  }
  __syncthreads();

  float o2[4][2] = {};
  for (int j = 0; j < 64; ++j) {
    float v0 = vs[j][tx * 2 + 0], v1 = vs[j][tx * 2 + 1];
#pragma unroll
    for (int ii = 0; ii < 4; ++ii) {
      float p = ps[ty * 4 + ii][j];
      o2[ii][0] += p * v0;
      o2[ii][1] += p * v1;
    }
  }
#pragma unroll
  for (int ii = 0; ii < 4; ++ii) {
    int l = win_map(w * 64 + ty * 4 + ii);
    obuf[l * 384 + head * 32 + tx * 2 + 0] = o2[ii][0];
    obuf[l * 384 + head * 32 + tx * 2 + 1] = o2[ii][1];
  }
}

// skip[o,h,w] = dot(hfin[(h*16+w)*384+:], skip_w[o*384+:]) + skip_b[o]
__global__ void skip_k(const float* __restrict__ hfin, const float* __restrict__ sw,
                       const float* __restrict__ sb, float* __restrict__ skipb) {
  int o = blockIdx.x, t = threadIdx.x;
  float acc = 0.f;
  for (int c = 0; c < 384; ++c) acc += hfin[t * 384 + c] * sw[o * 384 + c];
  skipb[o * 256 + t] = acc + sb[o];
}

// d1[o, h*16+k, w*16+l] = relu((dot_c + dt1_b[o]) * invs * bn1w[o] + bn1b[o])
__global__ void d1_k(const float* __restrict__ hfin, const float* __restrict__ wgt,
                     const float* __restrict__ bvec, const float* __restrict__ bnw,
                     const float* __restrict__ bnb, float* __restrict__ d1) {
  __shared__ float hs[2][384];
  const int t = threadIdx.x;
  const int l0 = blockIdx.x * 2;
  for (int idx = t; idx < 768; idx += 256) {
    int pi = idx / 384, c = idx % 384;
    hs[pi][c] = hfin[(l0 + pi) * 384 + c];
  }
  __syncthreads();
  const float invs = rsqrtf(1.0f + 1e-5f);
  const int kk = t >> 4, ll = t & 15;
  for (int o = 0; o < 3; ++o) {
    float a0 = 0.f, a1 = 0.f;
    for (int c = 0; c < 384; ++c) {
      float wv = wgt[c * 768 + o * 256 + t];
      a0 += hs[0][c] * wv;
      a1 += hs[1][c] * wv;
    }
    float sw = bnw[o] * invs, bb = bvec[o], sb = bnb[o];
    float v0 = fmaxf((a0 + bb) * sw + sb, 0.f);
    float v1 = fmaxf((a1 + bb) * sw + sb, 0.f);
#pragma unroll
    for (int pi = 0; pi < 2; ++pi) {
      int l = l0 + pi;
      int h = l >> 4, wq = l & 15;
      float v = pi ? v1 : v0;
      d1[o * 65536 + (h * 16 + kk) * 256 + (wq * 16 + ll)] = v;
    }
  }
}

// out[o,y,x] = (dot_c d1[c,y/16,x/16]*dt2w[c,o,y%16,x%16] + dt2b[o])*invs*bn2w[o]
//              + bn2b[o] + bilinear_ac(skip)(o,y,x);   one block per (y,o) row.
__launch_bounds__(256)
__global__ void d2_k(const float* __restrict__ d1, const float* __restrict__ w2,
                     const float* __restrict__ b2, const float* __restrict__ bnw,
                     const float* __restrict__ bnb, const float* __restrict__ skipb,
                     float* __restrict__ out) {
  __shared__ float d1s[3][256];
  __shared__ float wcol[3][16];
  __shared__ float srow[16];
  const int t = threadIdx.x;
  const int y = blockIdx.x, o = blockIdx.y;
  const int h2 = y >> 4, k = y & 15;
  for (int idx = t; idx < 768; idx += 256) {
    int c = idx >> 8, wi = idx & 255;
    d1s[c][wi] = d1[c * 65536 + h2 * 256 + wi];
  }
  if (t < 48) {
    int c = t >> 4, l2 = t & 15;
    wcol[c][l2] = w2[c * 1024 + o * 256 + k * 16 + l2];
  }
  if (t < 16) {
    const float dy = 15.0f / 4095.0f;
    float s = y * dy;
    int y0 = min((int)s, 15);
    int y1 = min(y0 + 1, 15);
    float wy = s - (float)y0;
    float a0 = skipb[o * 256 + y0 * 16 + t];
    float a1 = skipb[o * 256 + y1 * 16 + t];
    srow[t] = a0 + (a1 - a0) * wy;
  }
  __syncthreads();
  const float invs = rsqrtf(1.0f + 1e-5f);
  const float sw = bnw[o] * invs;
  const float base = b2[o] * sw + bnb[o];
  const float dx = 15.0f / 4095.0f;
  const size_t obase = ((size_t)o << 24) + ((size_t)y << 12);
#pragma unroll
  for (int rep = 0; rep < 4; ++rep) {
    int x4 = t + rep * 256;
    int x = x4 * 4;
    int wi = x >> 4;
    int l2b = x & 15;
    float vals[4];
#pragma unroll
    for (int e = 0; e < 4; ++e) {
      int l2 = l2b + e;
      float v = d1s[0][wi] * wcol[0][l2] + d1s[1][wi] * wcol[1][l2] + d1s[2][wi] * wcol[2][l2];
      v = v * sw + base;
      float s = (float)(x + e) * dx;
      int x0 = min((int)s, 15);
      int x1 = min(x0 + 1, 15);
      float wx = s - (float)x0;
      vals[e] = v + srow[x0] + (srow[x1] - srow[x0]) * wx;
    }
    *(float4*)&out[obase + x] = make_float4(vals[0], vals[1], vals[2], vals[3]);
  }
}

extern "C" void kernel_launch(void* const* d_in, const int* in_sizes, int n_in,
                              void* d_out, int out_size, void* d_ws, size_t ws_size,
                              hipStream_t stream) {
  const float* x       = (const float*)d_in[0];
  const float* patch_w = (const float*)d_in[1];
  const float* patch_b = (const float*)d_in[2];
  const float* pos     = (const float*)d_in[3];
  const float* ln1w    = (const float*)d_in[4];
  const float* ln1b    = (const float*)d_in[5];
  const float* qkvw    = (const float*)d_in[6];
  const float* projw   = (const float*)d_in[7];
  const float* projb   = (const float*)d_in[8];
  const float* rpb     = (const float*)d_in[9];
  const float* ln2w    = (const float*)d_in[10];
  const float* ln2b    = (const float*)d_in[11];
  const float* fc1w    = (const float*)d_in[12];
  const float* fc1b    = (const float*)d_in[13];
  const float* fc2w    = (const float*)d_in[14];
  const float* fc2b    = (const float*)d_in[15];
  const float* skipw   = (const float*)d_in[16];
  const float* skipbi  = (const float*)d_in[17];
  const float* dt1w    = (const float*)d_in[18];
  const float* dt1b    = (const float*)d_in[19];
  const float* bn1w    = (const float*)d_in[20];
  const float* bn1b    = (const float*)d_in[21];
  const float* dt2w    = (const float*)d_in[22];
  const float* dt2b    = (const float*)d_in[23];
  const float* bn2w    = (const float*)d_in[24];
  const float* bn2b    = (const float*)d_in[25];
  float* out = (float*)d_out;
  float* ws = (float*)d_ws;

  float* h    = ws;                // 98304
  float* qkvb = ws + 98304;        // 294912
  float* obuf = ws + 393216;       // 98304
  float* zb   = ws + 491520;       // 393216
  float* d1b  = ws + 884736;       // 196608
  float* skb  = ws + 1081344;      // 1024

  // patch embed: M=256 (h,w), N=384 (c), K=768 (inc,p,q); transposed store + pos add
  mgemm<2, 2, 2, 2, false, 3><<<dim3(6, 8), 256, 0, stream>>>(
      x, patch_w, patch_b, nullptr, nullptr, nullptr, pos, h, 384, 768);

  for (int b = 0; b < 12; ++b) {
    // qkv: LN1 + window-shift rows, N=1152, K=384
    mgemm<2, 2, 2, 1, true, 0><<<dim3(18, 8), 256, 0, stream>>>(
        h, qkvw + (size_t)b * 442368, nullptr, ln1w + b * 384, ln1b + b * 384,
        nullptr, nullptr, qkvb, 1152, 384);
    attn_k<<<48, 256, 0, stream>>>(qkvb, rpb + b * 2700, obuf);
    // proj: + bias + residual(h) -> h
    mgemm<1, 4, 1, 0, false, 1><<<dim3(6, 16), 256, 0, stream>>>(
        obuf, projw + (size_t)b * 147456, projb + b * 384, nullptr, nullptr,
        h, nullptr, h, 384, 384);
    // fc1: LN2 + gelu, N=1536, K=384
    mgemm<2, 2, 2, 0, true, 2><<<dim3(24, 8), 256, 0, stream>>>(
        h, fc1w + (size_t)b * 589824, fc1b + b * 1536, ln2w + b * 384, ln2b + b * 384,
        nullptr, nullptr, zb, 1536, 384);
    // fc2: + bias + residual(h) -> h, N=384, K=1536
    mgemm<1, 4, 1, 0, false, 1><<<dim3(6, 16), 256, 0, stream>>>(
        zb, fc2w + (size_t)b * 589824, fc2b + b * 384, nullptr, nullptr,
        h, nullptr, h, 384, 1536);
  }

  skip_k<<<4, 256, 0, stream>>>(h, skipw, skipbi, skb);
  d1_k<<<128, 256, 0, stream>>>(h, dt1w, dt1b, bn1w, bn1b, d1b);
  d2_k<<<dim3(4096, 4), 256, 0, stream>>>(d1b, dt2w, dt2b, bn2w, bn2b, skb, out);
}